// Round 1
// baseline (551.724 us; speedup 1.0000x reference)
//
#include <hip/hip_runtime.h>

#define LOG2E 1.44269504088896340736f

typedef _Float16 half2_t __attribute__((ext_vector_type(2)));

__device__ __forceinline__ unsigned pack2(float a, float b) {
    half2_t v; v.x = (_Float16)a; v.y = (_Float16)b;   // RNE (setup only)
    return __builtin_bit_cast(unsigned, v);
}
__device__ __forceinline__ half2_t ubc(unsigned u) {
    return __builtin_bit_cast(half2_t, u);
}

// DPP lane-xor moves (all stay inside a 32-lane half):
//   0x4E  quad_perm[2,3,0,1] = lane^2  -> pair^1
//   0x141 row_half_mirror    = lane^7  -> pair^3 (+pair-swap parity)
//   0x140 row_mirror         = lane^15 -> pair^7 (+pair-swap parity)
template <int CTRL>
__device__ __forceinline__ unsigned dppx(unsigned v) {
    return (unsigned)__builtin_amdgcn_mov_dpp((int)v, CTRL, 0xF, 0xF, true);
}

// lane^16 partner (within each 32-lane group) -> pair^8.
// xor-trick is convention-independent (same algebra as the round-9-verified
// permlane32_swap form). Fallback: ds_swizzle xor-16 (DS pipe).
__device__ __forceinline__ unsigned lanex16(unsigned u) {
#if __has_builtin(__builtin_amdgcn_permlane16_swap)
    auto r = __builtin_amdgcn_permlane16_swap(u, u, false, false);
    return (unsigned)(r[0] ^ r[1] ^ u);
#else
    return (unsigned)__builtin_amdgcn_ds_swizzle((int)u, 0x401F);
#endif
}

// Round-14: 2 sequences per wave (grid 512), gate-local lanes.
//   lane l: half hf=l>>5 -> sequence 2b+hf; kl=l&31 -> hidden unit kl.
//   Lane kl owns rows {kl, 32+kl, 64+kl, 96+kl} = i,f,g,o of unit kl:
//   the cell update is lane-local (no cross-half swap), and every
//   transcendental serves both sequences at once.
// h-broadcast is a register-only XOR-walk: after pack, every lane holds
// one f16 pair; two 8-hop DPP walkers (own start / ^16 start) cycle all
// 16 pairs through every lane. Weights are stored pre-permuted per lane
// (order + intra-pair swap matched to the walk), so no uniform broadcast
// and no LDS on the recurrence path.
__global__ __launch_bounds__(64, 1) void lstm_pl2_kernel(
    const float* __restrict__ x,      // [B, T]
    const float* __restrict__ W_ih,   // [128]
    const float* __restrict__ W_hh,   // [128, 32]
    const float* __restrict__ b_ih,   // [128]
    const float* __restrict__ b_hh,   // [128]
    const float* __restrict__ W_out,  // [32]
    const float* __restrict__ b_out,  // [1]
    float* __restrict__ out,          // [B, T]
    int T)
{
    __shared__ __align__(16) float psum[64 * 68];  // [step][col] raw h; A cols 0..31, B cols 36..67
    __shared__ float xs[2 * 72];                   // staged x chunk per half

    const int b  = blockIdx.x;
    const int l  = threadIdx.x;       // 0..63
    const int kl = l & 31;            // hidden unit index within half
    const int hf = l >> 5;            // 0 = seq 2b, 1 = seq 2b+1

    const float sA = -LOG2E;          // sigmoid prescale
    const float sG = -2.0f * LOG2E;   // tanh prescale

    const int ri = kl, rf2 = 32 + kl, rg = 64 + kl, ro = 96 + kl;

    // Accumulated lane-xor at each walk position (A: j=0..7, B: j=8..15).
    // Pair visited at j: (kl^X[j])>>1 ; intra-pair swap: (kl^X[j])&1.
    const int X[16] = {0,2,5,7,8,10,13,15, 16,18,21,23,24,26,29,31};

    unsigned wi[16], wf[16], wg[16], wo[16];
#pragma unroll
    for (int j = 0; j < 16; ++j) {
        const int xl = kl ^ X[j];
        const int q2 = xl & ~1;       // 2*pair
        const int s  = xl & 1;        // pair orientation at this hop
        wi[j] = pack2(W_hh[ri *32 + q2 + s] * sA, W_hh[ri *32 + q2 + (s^1)] * sA);
        wf[j] = pack2(W_hh[rf2*32 + q2 + s] * sA, W_hh[rf2*32 + q2 + (s^1)] * sA);
        wg[j] = pack2(W_hh[rg *32 + q2 + s] * sG, W_hh[rg *32 + q2 + (s^1)] * sG);
        wo[j] = pack2(W_hh[ro *32 + q2 + s] * sA, W_hh[ro *32 + q2 + (s^1)] * sA);
    }
#pragma unroll
    for (int j = 0; j < 16; ++j)
        asm volatile("" : "+v"(wi[j]), "+v"(wf[j]), "+v"(wg[j]), "+v"(wo[j]));  // pin; no remat

    float4 wout4[8];
#pragma unroll
    for (int m = 0; m < 8; ++m) wout4[m] = *(const float4*)(W_out + 4 * m);

    const float wxi = W_ih[ri ] * sA;
    const float wxf = W_ih[rf2] * sA;
    const float wxg = W_ih[rg ] * sG;
    const float wxo = W_ih[ro ] * sA;
    const float bi_ = (b_ih[ri ] + b_hh[ri ]) * sA;
    const float bf_ = (b_ih[rf2] + b_hh[rf2]) * sA;
    const float bg_ = (b_ih[rg ] + b_hh[rg ]) * sG;
    const float bo_ = (b_ih[ro ] + b_hh[ro ]) * sA;
    const float bout = b_out[0];

    const float* xpA = x + (size_t)(2*b)     * T;
    const float* xpB = x + (size_t)(2*b + 1) * T;
    float*       opA = out + (size_t)(2*b)     * T;
    float*       opB = out + (size_t)(2*b + 1) * T;

    float* xsh = xs + 72 * hf;            // uniform-per-half broadcast reads
    const int pcol = kl + 36 * hf;        // 36: keeps B rows 16B-aligned for epilogue b128

    // stage chunk 0 x (single wave: DS in-order, no barrier needed)
    xs[l]      = xpA[l];
    xs[72 + l] = xpB[l];

    float h = 0.0f, cs = 0.0f;            // cs = -2*log2e*c (scaled cell state)
    unsigned hpk = 0u;                    // own packed pair, loop-carried

    for (int t0 = 0; t0 < T; t0 += 64) {
        const int tn = (t0 + 64 < T) ? (t0 + 64) : t0;
        const float na = xpA[tn + l];     // prefetch next chunk
        const float nb = xpB[tn + l];

        float xt0 = xsh[0], xt1 = xsh[1]; // prime x pipeline

#pragma unroll 8
        for (int tu = 0; tu < 64; ++tu) {
            const float xt = (tu & 1) ? xt1 : xt0;
            float GiA = fmaf(wxi, xt, bi_);
            float GfA = fmaf(wxf, xt, bf_);
            float GgA = fmaf(wxg, xt, bg_);
            float GoA = fmaf(wxo, xt, bo_);
            float GiB = 0.0f, GfB = 0.0f, GgB = 0.0f, GoB = 0.0f;

            unsigned ha = hpk;            // walker A: pairs q0^{0..7}
            unsigned hb = lanex16(hpk);   // walker B: pairs q0^{8..15}

#define DOTS(j, HA, HB) \
            GiA = __builtin_amdgcn_fdot2(ubc(wi[j]),   ubc(HA), GiA, false); \
            GfA = __builtin_amdgcn_fdot2(ubc(wf[j]),   ubc(HA), GfA, false); \
            GgA = __builtin_amdgcn_fdot2(ubc(wg[j]),   ubc(HA), GgA, false); \
            GoA = __builtin_amdgcn_fdot2(ubc(wo[j]),   ubc(HA), GoA, false); \
            GiB = __builtin_amdgcn_fdot2(ubc(wi[8+j]), ubc(HB), GiB, false); \
            GfB = __builtin_amdgcn_fdot2(ubc(wf[8+j]), ubc(HB), GfB, false); \
            GgB = __builtin_amdgcn_fdot2(ubc(wg[8+j]), ubc(HB), GgB, false); \
            GoB = __builtin_amdgcn_fdot2(ubc(wo[8+j]), ubc(HB), GoB, false);

            DOTS(0, ha, hb)
            ha = dppx<0x4E>(ha);  hb = dppx<0x4E>(hb);
            DOTS(1, ha, hb)
            ha = dppx<0x141>(ha); hb = dppx<0x141>(hb);
            DOTS(2, ha, hb)
            ha = dppx<0x4E>(ha);  hb = dppx<0x4E>(hb);
            DOTS(3, ha, hb)
            ha = dppx<0x140>(ha); hb = dppx<0x140>(hb);
            DOTS(4, ha, hb)
            ha = dppx<0x4E>(ha);  hb = dppx<0x4E>(hb);
            DOTS(5, ha, hb)
            ha = dppx<0x141>(ha); hb = dppx<0x141>(hb);
            DOTS(6, ha, hb)
            ha = dppx<0x4E>(ha);  hb = dppx<0x4E>(hb);
            DOTS(7, ha, hb)
#undef DOTS

            const float Gi = GiA + GiB;
            const float Gf = GfA + GfB;
            const float Gg = GgA + GgB;
            const float Go = GoA + GoB;

            // all gates lane-local now: i,f,o sigmoid; gs = -2log2e*tanh(g)
            const float i_ = __builtin_amdgcn_rcpf(1.0f + __builtin_amdgcn_exp2f(Gi));
            const float f_ = __builtin_amdgcn_rcpf(1.0f + __builtin_amdgcn_exp2f(Gf));
            const float o_ = __builtin_amdgcn_rcpf(1.0f + __builtin_amdgcn_exp2f(Go));
            const float gs = fmaf(-4.0f * LOG2E,
                __builtin_amdgcn_rcpf(1.0f + __builtin_amdgcn_exp2f(Gg)),
                2.0f * LOG2E);

            cs = fmaf(f_, cs, i_ * gs);
            const float rc = __builtin_amdgcn_rcpf(1.0f + __builtin_amdgcn_exp2f(cs));
            h = fmaf(o_ + o_, rc, -o_);   // o*tanh(c) = 2o*rc - o

            // pack own pair for next step's walk (quad_perm[1,0,3,2])
            const float hn = __int_as_float(__builtin_amdgcn_mov_dpp(
                __float_as_int(h), 0xB1, 0xF, 0xF, true));
            hpk = __builtin_bit_cast(unsigned, __builtin_amdgcn_cvt_pkrtz(h, hn));

            psum[tu * 68 + pcol] = h;     // raw h; W_out in epilogue
            if (!(tu & 1)) xt0 = xsh[tu + 2]; else xt1 = xsh[tu + 2];  // x prefetch (2 ahead)
        }

        __syncthreads();  // single wave: cheap; drains psum
        // Epilogue: lane j computes out[t0+j] for each sequence.
#pragma unroll
        for (int s = 0; s < 2; ++s) {
            const float4* row = (const float4*)(psum + l * 68 + 36 * s);
            float4 a4;
            {
                float4 v4 = row[0];
                a4.x = v4.x * wout4[0].x; a4.y = v4.y * wout4[0].y;
                a4.z = v4.z * wout4[0].z; a4.w = v4.w * wout4[0].w;
            }
#pragma unroll
            for (int m = 1; m < 8; ++m) {
                float4 v4 = row[m];
                a4.x = fmaf(v4.x, wout4[m].x, a4.x);
                a4.y = fmaf(v4.y, wout4[m].y, a4.y);
                a4.z = fmaf(v4.z, wout4[m].z, a4.z);
                a4.w = fmaf(v4.w, wout4[m].w, a4.w);
            }
            const float r = (a4.x + a4.y) + (a4.z + a4.w) + bout;
            if (s == 0) opA[t0 + l] = r; else opB[t0 + l] = r;
        }
        __syncthreads();  // next chunk overwrites psum
        xs[l]      = na;  // stage next chunk x (in-order before next prime)
        xs[72 + l] = nb;
    }
}

extern "C" void kernel_launch(void* const* d_in, const int* in_sizes, int n_in,
                              void* d_out, int out_size, void* d_ws, size_t ws_size,
                              hipStream_t stream) {
    const float* x     = (const float*)d_in[0];   // [1024, 2048, 1]
    const float* W_ih  = (const float*)d_in[1];   // [128, 1]
    const float* W_hh  = (const float*)d_in[2];   // [128, 32]
    const float* b_ih  = (const float*)d_in[3];   // [128]
    const float* b_hh  = (const float*)d_in[4];   // [128]
    const float* W_out = (const float*)d_in[5];   // [1, 32]
    const float* b_out = (const float*)d_in[6];   // [1]
    float* out = (float*)d_out;                   // [1024, 2048, 1]

    const int B = 1024;
    const int T = 2048;
    lstm_pl2_kernel<<<B / 2, 64, 0, stream>>>(x, W_ih, W_hh, b_ih, b_hh,
                                              W_out, b_out, out, T);
}